// Round 7
// baseline (115.165 us; speedup 1.0000x reference)
//
#include <hip/hip_runtime.h>
#include <hip/hip_bf16.h>

#define BN 16
#define TN 2048
#define DN 64
#define EN 512
#define PAD 72   // bf16 row stride: 144B rows, 16B-aligned

using f32x4  = __attribute__((ext_vector_type(4))) float;
using bf16x8 = __attribute__((ext_vector_type(8))) short;
using bf16x4 = __attribute__((ext_vector_type(4))) short;

static __device__ __forceinline__ short f2bf(float f) {
    __hip_bfloat16 h = __float2bfloat16(f);
    return __builtin_bit_cast(short, h);
}
static __device__ __forceinline__ float bf2f(short s) {
    return __bfloat162float(__builtin_bit_cast(__hip_bfloat16, s));
}

// ---------------------------------------------------------------------------
// Kernel W: split W^T into bf16 hi + lo (WTh[n][k], WTl[n][k]). Unchanged.
// ---------------------------------------------------------------------------
__global__ __launch_bounds__(256) void wprep_kernel(
    const float* __restrict__ Wq, short* __restrict__ WTh,
    short* __restrict__ WTl)
{
    __shared__ float wlds[64][65];
    const int tid = threadIdx.x;
    const int k0 = blockIdx.x * 64;
    #pragma unroll
    for (int it = 0; it < 16; ++it) {
        int idx = it * 256 + tid;
        int k = idx >> 6, n = idx & 63;
        wlds[k][n] = Wq[(size_t)(k0 + k) * 64 + n];
    }
    __syncthreads();
    #pragma unroll
    for (int it = 0; it < 16; ++it) {
        int idx = it * 256 + tid;
        int n = idx >> 6, k = idx & 63;
        float v = wlds[k][n];
        short h = f2bf(v);
        short l = f2bf(v - bf2f(h));
        WTh[(size_t)n * EN + k0 + k] = h;
        WTl[(size_t)n * EN + k0 + k] = l;
    }
}

// ---------------------------------------------------------------------------
// Kernel A: Q = x @ W + bq via MFMA (bf16 hi+lo W, f32 accum). Unchanged.
// ---------------------------------------------------------------------------
__global__ __launch_bounds__(256, 2) void qproj_kernel(
    const float* __restrict__ x, const short* __restrict__ WTh,
    const short* __restrict__ WTl, const float* __restrict__ bq,
    short* __restrict__ Qb, short* __restrict__ QTb)
{
    __shared__ short xh[64 * 40];
    __shared__ short wth[64 * 40];
    __shared__ short wtl[64 * 40];
    __shared__ short tl[64][68];

    const int tid = threadIdx.x;
    const int lane = tid & 63;
    const int wv = tid >> 6;
    const int c = lane & 15;
    const int g = lane >> 4;
    const int rowbase = blockIdx.x * 64;
    const int b = rowbase >> 11;
    const int tbase = rowbase & (TN - 1);

    const int sr = tid >> 3;
    const int sc4 = tid & 7;

    float4 xa = *reinterpret_cast<const float4*>(&x[(size_t)(rowbase + sr) * EN + sc4 * 4]);
    float4 xb = *reinterpret_cast<const float4*>(&x[(size_t)(rowbase + 32 + sr) * EN + sc4 * 4]);
    bf16x4 wa = *reinterpret_cast<const bf16x4*>(&WTh[(size_t)sr * EN + sc4 * 4]);
    bf16x4 wb = *reinterpret_cast<const bf16x4*>(&WTh[(size_t)(32 + sr) * EN + sc4 * 4]);
    bf16x4 la = *reinterpret_cast<const bf16x4*>(&WTl[(size_t)sr * EN + sc4 * 4]);
    bf16x4 lb = *reinterpret_cast<const bf16x4*>(&WTl[(size_t)(32 + sr) * EN + sc4 * 4]);

    f32x4 acc[4];
    #pragma unroll
    for (int nt = 0; nt < 4; ++nt) acc[nt] = (f32x4){0.f, 0.f, 0.f, 0.f};

    for (int ks = 0; ks < EN; ks += 32) {
        __syncthreads();
        bf16x4 h0, h1;
        #pragma unroll
        for (int j = 0; j < 4; ++j) { h0[j] = f2bf(xa[j]); h1[j] = f2bf(xb[j]); }
        *reinterpret_cast<bf16x4*>(&xh[sr * 40 + sc4 * 4]) = h0;
        *reinterpret_cast<bf16x4*>(&xh[(32 + sr) * 40 + sc4 * 4]) = h1;
        *reinterpret_cast<bf16x4*>(&wth[sr * 40 + sc4 * 4]) = wa;
        *reinterpret_cast<bf16x4*>(&wth[(32 + sr) * 40 + sc4 * 4]) = wb;
        *reinterpret_cast<bf16x4*>(&wtl[sr * 40 + sc4 * 4]) = la;
        *reinterpret_cast<bf16x4*>(&wtl[(32 + sr) * 40 + sc4 * 4]) = lb;

        const int kn = (ks + 32 < EN) ? ks + 32 : ks;
        xa = *reinterpret_cast<const float4*>(&x[(size_t)(rowbase + sr) * EN + kn + sc4 * 4]);
        xb = *reinterpret_cast<const float4*>(&x[(size_t)(rowbase + 32 + sr) * EN + kn + sc4 * 4]);
        wa = *reinterpret_cast<const bf16x4*>(&WTh[(size_t)sr * EN + kn + sc4 * 4]);
        wb = *reinterpret_cast<const bf16x4*>(&WTh[(size_t)(32 + sr) * EN + kn + sc4 * 4]);
        la = *reinterpret_cast<const bf16x4*>(&WTl[(size_t)sr * EN + kn + sc4 * 4]);
        lb = *reinterpret_cast<const bf16x4*>(&WTl[(size_t)(32 + sr) * EN + kn + sc4 * 4]);
        __syncthreads();

        bf16x8 av = *reinterpret_cast<const bf16x8*>(&xh[(wv * 16 + c) * 40 + g * 8]);
        #pragma unroll
        for (int nt = 0; nt < 4; ++nt) {
            bf16x8 bh = *reinterpret_cast<const bf16x8*>(&wth[(nt * 16 + c) * 40 + g * 8]);
            bf16x8 bl = *reinterpret_cast<const bf16x8*>(&wtl[(nt * 16 + c) * 40 + g * 8]);
            acc[nt] = __builtin_amdgcn_mfma_f32_16x16x32_bf16(av, bh, acc[nt], 0, 0, 0);
            acc[nt] = __builtin_amdgcn_mfma_f32_16x16x32_bf16(av, bl, acc[nt], 0, 0, 0);
        }
    }

    __syncthreads();
    #pragma unroll
    for (int nt = 0; nt < 4; ++nt) {
        const float bias = bq[nt * 16 + c];
        #pragma unroll
        for (int r = 0; r < 4; ++r) {
            const int row = wv * 16 + g * 4 + r;
            short qb = f2bf(acc[nt][r] + bias);
            Qb[(size_t)(rowbase + row) * DN + nt * 16 + c] = qb;
            tl[nt * 16 + c][row] = qb;
        }
    }
    __syncthreads();
    #pragma unroll
    for (int it = 0; it < 4; ++it) {
        int idx = it * 256 + tid;
        int d = idx >> 4;
        int j4 = (idx & 15) * 4;
        *reinterpret_cast<short4*>(&QTb[((size_t)(b * 64 + d)) * TN + tbase + j4]) =
            *reinterpret_cast<const short4*>(&tl[d][j4]);
    }
}

// ---------------------------------------------------------------------------
// Kernel B (v5): partial column-softmax sums. Grid (TN/64, BN, 2): block owns
// 64 j-rows, z-split halves the i-range (16 iters). Partial row-sums written
// to l_part[z][b][t] (each slot written by exactly one block -> no atomics).
// ---------------------------------------------------------------------------
__global__ __launch_bounds__(256, 4) void stats_kernel(
    const short* __restrict__ Qb, float* __restrict__ l_part)
{
    __shared__ short Qt[64 * PAD];
    const int tid = threadIdx.x;
    const int lane = tid & 63;
    const int wv = tid >> 6;
    const int c = lane & 15;
    const int g = lane >> 4;
    const int b = blockIdx.y;
    const int z = blockIdx.z;
    const int jbase = blockIdx.x * 64 + wv * 16;
    const short* Qbb = Qb + (size_t)b * TN * DN;

    bf16x8 a0 = *reinterpret_cast<const bf16x8*>(Qbb + (size_t)(jbase + c) * DN + g * 8);
    bf16x8 a1 = *reinterpret_cast<const bf16x8*>(Qbb + (size_t)(jbase + c) * DN + g * 8 + 32);

    const int srow = tid >> 2;
    const int schk = tid & 3;
    const int ilo = z * (TN / 2);

    bf16x8 v0 = *reinterpret_cast<const bf16x8*>(Qbb + (size_t)(ilo + srow) * DN + schk * 16);
    bf16x8 v1 = *reinterpret_cast<const bf16x8*>(Qbb + (size_t)(ilo + srow) * DN + schk * 16 + 8);

    float l[4] = {0.f, 0.f, 0.f, 0.f};
    for (int ii = 0; ii < TN / 2; ii += 64) {
        __syncthreads();
        *reinterpret_cast<bf16x8*>(&Qt[srow * PAD + schk * 16]) = v0;
        *reinterpret_cast<bf16x8*>(&Qt[srow * PAD + schk * 16 + 8]) = v1;
        const int in_ = ilo + ((ii + 64 < TN / 2) ? ii + 64 : ii);
        v0 = *reinterpret_cast<const bf16x8*>(Qbb + (size_t)(in_ + srow) * DN + schk * 16);
        v1 = *reinterpret_cast<const bf16x8*>(Qbb + (size_t)(in_ + srow) * DN + schk * 16 + 8);
        __syncthreads();

        #pragma unroll
        for (int it = 0; it < 4; ++it) {
            bf16x8 b0 = *reinterpret_cast<const bf16x8*>(&Qt[(it * 16 + c) * PAD + g * 8]);
            bf16x8 b1 = *reinterpret_cast<const bf16x8*>(&Qt[(it * 16 + c) * PAD + g * 8 + 32]);
            f32x4 acc = {0.f, 0.f, 0.f, 0.f};
            acc = __builtin_amdgcn_mfma_f32_16x16x32_bf16(a0, b0, acc, 0, 0, 0);
            acc = __builtin_amdgcn_mfma_f32_16x16x32_bf16(a1, b1, acc, 0, 0, 0);
            #pragma unroll
            for (int r = 0; r < 4; ++r)
                l[r] += __expf(acc[r] * 0.125f);
        }
    }
    #pragma unroll
    for (int r = 0; r < 4; ++r) {
        float v = l[r];
        v += __shfl_xor(v, 1);
        v += __shfl_xor(v, 2);
        v += __shfl_xor(v, 4);
        v += __shfl_xor(v, 8);
        l[r] = v;
    }
    if (c == 0) {
        #pragma unroll
        for (int r = 0; r < 4; ++r)
            l_part[((size_t)z * BN + b) * TN + jbase + g * 4 + r] = l[r];
    }
}

// ---------------------------------------------------------------------------
// Kernel F: RT[b][d][j] = (1 / (l_part[0][b][j] + l_part[1][b][j])) * QT[b][d][j]
// Folds the softmax denominator into the V-operand once (saves pv's lv path).
// ---------------------------------------------------------------------------
__global__ __launch_bounds__(256) void fuse_kernel(
    const short* __restrict__ QTb, const float* __restrict__ l_part,
    short* __restrict__ RT)
{
    const int idx = blockIdx.x * 256 + threadIdx.x;   // 0..262143
    const int c8 = idx & 255;                          // j-chunk (8 wide)
    const int bd = idx >> 8;                           // b*64 + d
    const int b = bd >> 6;
    const int j0 = c8 * 8;

    bf16x8 q = *reinterpret_cast<const bf16x8*>(&QTb[(size_t)bd * TN + j0]);
    const float* lp0 = l_part + (size_t)b * TN + j0;
    const float* lp1 = l_part + (size_t)(BN + b) * TN + j0;
    bf16x8 r;
    #pragma unroll
    for (int t = 0; t < 8; ++t)
        r[t] = f2bf(bf2f(q[t]) / (lp0[t] + lp1[t]));
    *reinterpret_cast<bf16x8*>(&RT[(size_t)bd * TN + j0]) = r;
}

// ---------------------------------------------------------------------------
// Kernel C (v5): out[i,:] += sum_{j in half} exp(S[i,j]/8) * RT[:,j]
// Grid (TN/64, BN, 2): 1024 blocks (4/CU). z halves the j-range (16 iters).
// RT A-frags preloaded into regs BEFORE phase A (overlaps the Pt wait).
// Epilogue: f32 atomicAdd into zeroed out (2 commutative adds/element).
// ---------------------------------------------------------------------------
__global__ __launch_bounds__(256, 4) void pv_kernel(
    const short* __restrict__ Qb, const short* __restrict__ RT,
    float* __restrict__ out)
{
    __shared__ short Qt[64 * PAD];        // Q[j-local][d]
    __shared__ short RTt[64 * PAD];       // RT[d][j-local]
    __shared__ short Pt[4][16 * PAD];     // per wave: P[i-local][j-local]

    const int tid = threadIdx.x;
    const int lane = tid & 63;
    const int wv = tid >> 6;
    const int c = lane & 15;
    const int g = lane >> 4;
    const int b = blockIdx.y;
    const int z = blockIdx.z;
    const int ibase = blockIdx.x * 64 + wv * 16;
    const short* Qbb = Qb + (size_t)b * TN * DN;
    const short* RTb = RT + (size_t)b * DN * TN;

    bf16x8 bi0 = *reinterpret_cast<const bf16x8*>(Qbb + (size_t)(ibase + c) * DN + g * 8);
    bf16x8 bi1 = *reinterpret_cast<const bf16x8*>(Qbb + (size_t)(ibase + c) * DN + g * 8 + 32);

    f32x4 o[4];
    #pragma unroll
    for (int dt = 0; dt < 4; ++dt) o[dt] = (f32x4){0.f, 0.f, 0.f, 0.f};

    const int srow = tid >> 2;
    const int schk = tid & 3;
    const int jlo = z * (TN / 2);

    bf16x8 vq0 = *reinterpret_cast<const bf16x8*>(Qbb + (size_t)(jlo + srow) * DN + schk * 16);
    bf16x8 vq1 = *reinterpret_cast<const bf16x8*>(Qbb + (size_t)(jlo + srow) * DN + schk * 16 + 8);
    bf16x8 vt0 = *reinterpret_cast<const bf16x8*>(RTb + (size_t)srow * TN + jlo + schk * 16);
    bf16x8 vt1 = *reinterpret_cast<const bf16x8*>(RTb + (size_t)srow * TN + jlo + schk * 16 + 8);

    for (int jj = 0; jj < TN / 2; jj += 64) {
        __syncthreads();
        *reinterpret_cast<bf16x8*>(&Qt[srow * PAD + schk * 16]) = vq0;
        *reinterpret_cast<bf16x8*>(&Qt[srow * PAD + schk * 16 + 8]) = vq1;
        *reinterpret_cast<bf16x8*>(&RTt[srow * PAD + schk * 16]) = vt0;
        *reinterpret_cast<bf16x8*>(&RTt[srow * PAD + schk * 16 + 8]) = vt1;

        const int jn = jlo + ((jj + 64 < TN / 2) ? jj + 64 : jj);
        vq0 = *reinterpret_cast<const bf16x8*>(Qbb + (size_t)(jn + srow) * DN + schk * 16);
        vq1 = *reinterpret_cast<const bf16x8*>(Qbb + (size_t)(jn + srow) * DN + schk * 16 + 8);
        vt0 = *reinterpret_cast<const bf16x8*>(RTb + (size_t)srow * TN + jn + schk * 16);
        vt1 = *reinterpret_cast<const bf16x8*>(RTb + (size_t)srow * TN + jn + schk * 16 + 8);
        __syncthreads();

        // preload phase-B A-frags (RT rows) so the Pt wait doesn't stall them
        bf16x8 aq[4][2];
        #pragma unroll
        for (int dt = 0; dt < 4; ++dt) {
            aq[dt][0] = *reinterpret_cast<const bf16x8*>(&RTt[(dt * 16 + c) * PAD + g * 8]);
            aq[dt][1] = *reinterpret_cast<const bf16x8*>(&RTt[(dt * 16 + c) * PAD + 32 + g * 8]);
        }

        // --- phase A: MFMA1 S^T tiles -> P = exp(s/8) -> Pt (wave-private) ---
        #pragma unroll
        for (int jt = 0; jt < 4; ++jt) {
            bf16x8 a0 = *reinterpret_cast<const bf16x8*>(&Qt[(jt * 16 + c) * PAD + g * 8]);
            bf16x8 a1 = *reinterpret_cast<const bf16x8*>(&Qt[(jt * 16 + c) * PAD + g * 8 + 32]);
            f32x4 accs = {0.f, 0.f, 0.f, 0.f};
            accs = __builtin_amdgcn_mfma_f32_16x16x32_bf16(a0, bi0, accs, 0, 0, 0);
            accs = __builtin_amdgcn_mfma_f32_16x16x32_bf16(a1, bi1, accs, 0, 0, 0);
            bf16x4 pw;
            #pragma unroll
            for (int r = 0; r < 4; ++r)
                pw[r] = f2bf(__expf(accs[r] * 0.125f));
            *reinterpret_cast<bf16x4*>(&Pt[wv][c * PAD + jt * 16 + g * 4]) = pw;
        }
        asm volatile("s_waitcnt lgkmcnt(0)" ::: "memory");
        __builtin_amdgcn_sched_barrier(0);

        // --- phase B: MFMA2 outT[d][i] += RT[d][j] * P[j][i] ---
        bf16x8 p0 = *reinterpret_cast<const bf16x8*>(&Pt[wv][c * PAD + g * 8]);
        bf16x8 p1 = *reinterpret_cast<const bf16x8*>(&Pt[wv][c * PAD + 32 + g * 8]);
        #pragma unroll
        for (int dt = 0; dt < 4; ++dt) {
            o[dt] = __builtin_amdgcn_mfma_f32_16x16x32_bf16(aq[dt][0], p0, o[dt], 0, 0, 0);
            o[dt] = __builtin_amdgcn_mfma_f32_16x16x32_bf16(aq[dt][1], p1, o[dt], 0, 0, 0);
        }
    }

    // epilogue: atomic accumulate outT[dt*16+g*4+r][ibase+c] into out
    float* outb = out + (size_t)b * TN * DN;
    #pragma unroll
    for (int dt = 0; dt < 4; ++dt) {
        #pragma unroll
        for (int r = 0; r < 4; ++r)
            atomicAdd(&outb[(size_t)(ibase + c) * DN + dt * 16 + g * 4 + r], o[dt][r]);
    }
}

extern "C" void kernel_launch(void* const* d_in, const int* in_sizes, int n_in,
                              void* d_out, int out_size, void* d_ws, size_t ws_size,
                              hipStream_t stream) {
    const float* x  = (const float*)d_in[0];
    const float* Wq = (const float*)d_in[1];
    const float* bq = (const float*)d_in[2];
    float* out = (float*)d_out;

    short* Qb   = (short*)d_ws;                           // 4 MB
    short* QTb  = Qb + (size_t)BN * TN * DN;              // 4 MB
    short* RT   = QTb + (size_t)BN * TN * DN;             // 4 MB
    float* lpar = (float*)(RT + (size_t)BN * TN * DN);    // 256 KB
    short* WTh  = (short*)(lpar + (size_t)2 * BN * TN);   // 64 KB
    short* WTl  = WTh + (size_t)DN * EN;                  // 64 KB

    hipMemsetAsync(out, 0, (size_t)out_size * sizeof(float), stream);
    wprep_kernel<<<dim3(EN / 64), dim3(256), 0, stream>>>(Wq, WTh, WTl);
    qproj_kernel<<<dim3(BN * TN / 64), dim3(256), 0, stream>>>(x, WTh, WTl, bq, Qb, QTb);
    stats_kernel<<<dim3(TN / 64, BN, 2), dim3(256), 0, stream>>>(Qb, lpar);
    fuse_kernel<<<dim3(BN * DN * TN / 8 / 256), dim3(256), 0, stream>>>(QTb, lpar, RT);
    pv_kernel<<<dim3(TN / 64, BN, 2), dim3(256), 0, stream>>>(Qb, RT, out);
}